// Round 4
// baseline (5175.860 us; speedup 1.0000x reference)
//
#include <hip/hip_runtime.h>
#include <hip/hip_bf16.h>
#include <math.h>

#define TT 12
#define NN 50000
#define EE 800000
#define CC 128
#define HH 128

// ---------------- bf16 helpers (manual, RNE) --------------------------------
__device__ __forceinline__ unsigned f2bf(float f) {
    unsigned u = __float_as_uint(f);
    return (u + 0x7FFFu + ((u >> 16) & 1u)) >> 16;
}
__device__ __forceinline__ float bf_lo(unsigned p) {
    return __uint_as_float(p << 16);
}
__device__ __forceinline__ float bf_hi(unsigned p) {
    return __uint_as_float(p & 0xFFFF0000u);
}

// ---------------------------------------------------------------------------
// Per-timestep graph prep
// ---------------------------------------------------------------------------

__global__ void zero_counts(int* __restrict__ count, float* __restrict__ gslot, int n) {
    int i = blockIdx.x * 256 + threadIdx.x;
    if (i < n) count[i] = 0;
    if (blockIdx.x == 0 && threadIdx.x < HH) gslot[threadIdx.x] = 0.0f;
}

__global__ void count_edges(const int* __restrict__ dst, int* __restrict__ count, int ne) {
    int e = blockIdx.x * 256 + threadIdx.x;
    if (e < ne) atomicAdd(&count[dst[e]], 1);
}

__global__ __launch_bounds__(256) void scan1(const int* __restrict__ count,
                                             int* __restrict__ rp,
                                             int* __restrict__ bsum, int n) {
    __shared__ int sh[256];
    int tid = threadIdx.x;
    int base = blockIdx.x * 1024 + tid * 4;
    int v0 = (base + 0 < n) ? count[base + 0] : 0;
    int v1 = (base + 1 < n) ? count[base + 1] : 0;
    int v2 = (base + 2 < n) ? count[base + 2] : 0;
    int v3 = (base + 3 < n) ? count[base + 3] : 0;
    int ts = v0 + v1 + v2 + v3;
    sh[tid] = ts;
    __syncthreads();
    for (int off = 1; off < 256; off <<= 1) {
        int v = (tid >= off) ? sh[tid - off] : 0;
        __syncthreads();
        sh[tid] += v;
        __syncthreads();
    }
    int excl = sh[tid] - ts;
    if (base + 0 < n) rp[base + 0] = excl;
    if (base + 1 < n) rp[base + 1] = excl + v0;
    if (base + 2 < n) rp[base + 2] = excl + v0 + v1;
    if (base + 3 < n) rp[base + 3] = excl + v0 + v1 + v2;
    if (tid == 255) bsum[blockIdx.x] = sh[255];
}

__global__ __launch_bounds__(256) void scan2(int* __restrict__ bsum, int* __restrict__ rp,
                                             int nb, int n, int etot) {
    __shared__ int sh[256];
    int tid = threadIdx.x;
    int v = (tid < nb) ? bsum[tid] : 0;
    sh[tid] = v;
    __syncthreads();
    for (int off = 1; off < 256; off <<= 1) {
        int x = (tid >= off) ? sh[tid - off] : 0;
        __syncthreads();
        sh[tid] += x;
        __syncthreads();
    }
    if (tid < nb) bsum[tid] = sh[tid] - v;  // exclusive
    if (tid == 0) rp[n] = etot;
}

__global__ void scan3(int* __restrict__ rp, int* __restrict__ work,
                      const int* __restrict__ bsum, const int* __restrict__ count,
                      float* __restrict__ dinv, int n) {
    int i = blockIdx.x * 256 + threadIdx.x;
    if (i < n) {
        int v = rp[i] + bsum[i >> 10];
        rp[i] = v;
        work[i] = v;
        dinv[i] = rsqrtf(1.0f + (float)count[i]);
    }
}

__global__ void fill_csr(const int* __restrict__ src, const int* __restrict__ dst,
                         int* __restrict__ work, int* __restrict__ csr_src, int ne) {
    int e = blockIdx.x * 256 + threadIdx.x;
    if (e < ne) {
        int d = dst[e];
        int pos = atomicAdd(&work[d], 1);
        csr_src[pos] = src[e];
    }
}

// ---------------------------------------------------------------------------
// GEMM: Y[row][c] = bf16( dinv[row] * sum_k X[row][k] * W[k][c] )
// 256 threads, 128 rows/block; thread = 4 rows x 16 cols (register-blocked).
// W staged in LDS with per-row permute so each wave instruction's 8 distinct
// 16B reads are contiguous 128B (conflict-free + 8-way broadcast):
//   Ws[k*128 + j*32 + cg*4 + l] = W[k][cg*16 + j*4 + l]
// ---------------------------------------------------------------------------
template<bool XBF16>
__global__ __launch_bounds__(256) void gemm_scale_k(const void* __restrict__ Xv,
                                                    const float* __restrict__ W,
                                                    const float* __restrict__ dinv,
                                                    unsigned* __restrict__ Yb,
                                                    int nrows) {
    __shared__ float Ws[128 * 128];
    int tid = threadIdx.x;
    for (int i = tid * 4; i < 128 * 128; i += 256 * 4) {
        int c = i & 127;
        float4 v = *(const float4*)&W[i];
        *(float4*)&Ws[(i & ~127) + ((c >> 2) & 3) * 32 + (c >> 4) * 4] = v;
    }
    __syncthreads();

    const int cg = tid & 7;
    const int r0 = blockIdx.x * 128 + (tid >> 3) * 4;
    if (r0 >= nrows) return;

    float acc[4][16];
#pragma unroll
    for (int r = 0; r < 4; ++r)
#pragma unroll
        for (int c = 0; c < 16; ++c) acc[r][c] = 0.f;

    const float* Xf = (const float*)Xv;
    const unsigned* Xb = (const unsigned*)Xv;

    for (int k0 = 0; k0 < 128; k0 += 4) {
        float xv[4][4];
#pragma unroll
        for (int r = 0; r < 4; ++r) {
            int row = r0 + r;
            if (row < nrows) {
                if (XBF16) {
                    uint2 p = *(const uint2*)&Xb[(size_t)row * 64 + (k0 >> 1)];
                    xv[r][0] = bf_lo(p.x); xv[r][1] = bf_hi(p.x);
                    xv[r][2] = bf_lo(p.y); xv[r][3] = bf_hi(p.y);
                } else {
                    float4 q = *(const float4*)&Xf[(size_t)row * 128 + k0];
                    xv[r][0] = q.x; xv[r][1] = q.y; xv[r][2] = q.z; xv[r][3] = q.w;
                }
            } else {
                xv[r][0] = xv[r][1] = xv[r][2] = xv[r][3] = 0.f;
            }
        }
#pragma unroll
        for (int kk = 0; kk < 4; ++kk) {
            const float* wrow = &Ws[((k0 + kk) << 7) + cg * 4];
            float4 w0 = *(const float4*)(wrow);
            float4 w1 = *(const float4*)(wrow + 32);
            float4 w2 = *(const float4*)(wrow + 64);
            float4 w3 = *(const float4*)(wrow + 96);
#pragma unroll
            for (int r = 0; r < 4; ++r) {
                float xs = xv[r][kk];
                acc[r][0]  += xs * w0.x; acc[r][1]  += xs * w0.y;
                acc[r][2]  += xs * w0.z; acc[r][3]  += xs * w0.w;
                acc[r][4]  += xs * w1.x; acc[r][5]  += xs * w1.y;
                acc[r][6]  += xs * w1.z; acc[r][7]  += xs * w1.w;
                acc[r][8]  += xs * w2.x; acc[r][9]  += xs * w2.y;
                acc[r][10] += xs * w2.z; acc[r][11] += xs * w2.w;
                acc[r][12] += xs * w3.x; acc[r][13] += xs * w3.y;
                acc[r][14] += xs * w3.z; acc[r][15] += xs * w3.w;
            }
        }
    }

#pragma unroll
    for (int r = 0; r < 4; ++r) {
        int row = r0 + r;
        if (row >= nrows) continue;
        float dv = dinv[row];
        unsigned o[8];
#pragma unroll
        for (int p = 0; p < 8; ++p) {
            o[p] = f2bf(acc[r][2 * p] * dv) | (f2bf(acc[r][2 * p + 1] * dv) << 16);
        }
        unsigned* yrow = Yb + (size_t)row * 64 + cg * 8;
        *(uint4*)(yrow + 0) = make_uint4(o[0], o[1], o[2], o[3]);
        *(uint4*)(yrow + 4) = make_uint4(o[4], o[5], o[6], o[7]);
    }
}

// ---------------------------------------------------------------------------
// Aggregation over bf16 message table Ys (row = 64 uints = 128 bf16).
// out[d] = relu(dinv[d] * (Ys[d] + sum_src Ys[src]) + b); 1 wave per node.
// ---------------------------------------------------------------------------
__global__ __launch_bounds__(256) void agg_relu(const unsigned* __restrict__ Ys,
                                                const int* __restrict__ csr_src,
                                                const int* __restrict__ row_ptr,
                                                const float* __restrict__ dinv,
                                                const float* __restrict__ bias,
                                                unsigned* __restrict__ Hout, int n) {
    int wave = threadIdx.x >> 6;
    int lane = threadIdx.x & 63;
    float bx = bias[lane * 2], by = bias[lane * 2 + 1];
    int d0 = blockIdx.x * 16 + wave * 4;
#pragma unroll
    for (int cnt = 0; cnt < 4; ++cnt) {
        int d = d0 + cnt;
        if (d >= n) break;
        unsigned sv = Ys[(size_t)d * 64 + lane];
        float ax = bf_lo(sv), ay = bf_hi(sv);
        float a2x = 0.f, a2y = 0.f;
        int e = row_ptr[d], e1 = row_ptr[d + 1];
        for (; e + 1 < e1; e += 2) {
            unsigned v0 = Ys[(size_t)csr_src[e] * 64 + lane];
            unsigned v1 = Ys[(size_t)csr_src[e + 1] * 64 + lane];
            ax += bf_lo(v0); ay += bf_hi(v0);
            a2x += bf_lo(v1); a2y += bf_hi(v1);
        }
        if (e < e1) {
            unsigned v0 = Ys[(size_t)csr_src[e] * 64 + lane];
            ax += bf_lo(v0); ay += bf_hi(v0);
        }
        float dv = dinv[d];
        float ox = fmaxf((ax + a2x) * dv + bx, 0.f);
        float oy = fmaxf((ay + a2y) * dv + by, 0.f);
        Hout[(size_t)d * 64 + lane] = f2bf(ox) | (f2bf(oy) << 16);
    }
}

// Pool variant: grid-stride over nodes (few blocks -> few atomics), relu'd
// rows summed into gout[128] via one atomicAdd per (block, channel).
#define POOLB 512
__global__ __launch_bounds__(256) void agg_relu_pool(const unsigned* __restrict__ Ys,
                                                     const int* __restrict__ csr_src,
                                                     const int* __restrict__ row_ptr,
                                                     const float* __restrict__ dinv,
                                                     const float* __restrict__ bias,
                                                     float* __restrict__ gout, int n) {
    __shared__ float pool[4][128];
    int wave = threadIdx.x >> 6;
    int lane = threadIdx.x & 63;
    float bx = bias[lane * 2], by = bias[lane * 2 + 1];
    float px = 0.f, py = 0.f;
    for (int base = blockIdx.x * 16; base < n; base += POOLB * 16) {
        int d0 = base + wave * 4;
#pragma unroll
        for (int cnt = 0; cnt < 4; ++cnt) {
            int d = d0 + cnt;
            if (d >= n) break;
            unsigned sv = Ys[(size_t)d * 64 + lane];
            float ax = bf_lo(sv), ay = bf_hi(sv);
            float a2x = 0.f, a2y = 0.f;
            int e = row_ptr[d], e1 = row_ptr[d + 1];
            for (; e + 1 < e1; e += 2) {
                unsigned v0 = Ys[(size_t)csr_src[e] * 64 + lane];
                unsigned v1 = Ys[(size_t)csr_src[e + 1] * 64 + lane];
                ax += bf_lo(v0); ay += bf_hi(v0);
                a2x += bf_lo(v1); a2y += bf_hi(v1);
            }
            if (e < e1) {
                unsigned v0 = Ys[(size_t)csr_src[e] * 64 + lane];
                ax += bf_lo(v0); ay += bf_hi(v0);
            }
            float dv = dinv[d];
            px += fmaxf((ax + a2x) * dv + bx, 0.f);
            py += fmaxf((ay + a2y) * dv + by, 0.f);
        }
    }
    pool[wave][lane * 2] = px;
    pool[wave][lane * 2 + 1] = py;
    __syncthreads();
    int tid = threadIdx.x;
    if (tid < 128) {
        float s = pool[0][tid] + pool[1][tid] + pool[2][tid] + pool[3][tid];
        atomicAdd(&gout[tid], s);
    }
}

// ---------------------------------------------------------------------------
// GRU over T=12 steps + head. Single block, 384 threads.
// ---------------------------------------------------------------------------
__global__ __launch_bounds__(384) void gru_head(const float* __restrict__ gseq,
                                                const float* __restrict__ W_ih,
                                                const float* __restrict__ W_hh,
                                                const float* __restrict__ b_ih,
                                                const float* __restrict__ b_hh,
                                                const float* __restrict__ W_head,
                                                const float* __restrict__ b_head,
                                                float* __restrict__ out) {
    __shared__ float xs[128], hs[128], gi[384], gh[384];
    int tid = threadIdx.x;
    if (tid < 128) hs[tid] = 0.0f;
    __syncthreads();
    const float inv_n = 1.0f / (float)NN;
    for (int t = 0; t < TT; ++t) {
        if (tid < 128) xs[tid] = gseq[t * 128 + tid] * inv_n;
        __syncthreads();
        float a = b_ih[tid];
        float b = b_hh[tid];
        const float* wi = W_ih + (size_t)tid * 128;
        const float* wh = W_hh + (size_t)tid * 128;
        for (int k = 0; k < 128; k += 4) {
            float4 wiv = *(const float4*)(wi + k);
            float4 whv = *(const float4*)(wh + k);
            float4 xv = *(const float4*)(xs + k);
            float4 hv = *(const float4*)(hs + k);
            a += wiv.x * xv.x + wiv.y * xv.y + wiv.z * xv.z + wiv.w * xv.w;
            b += whv.x * hv.x + whv.y * hv.y + whv.z * hv.z + whv.w * hv.w;
        }
        gi[tid] = a;
        gh[tid] = b;
        __syncthreads();
        if (tid < 128) {
            float r = 1.0f / (1.0f + expf(-(gi[tid] + gh[tid])));
            float z = 1.0f / (1.0f + expf(-(gi[128 + tid] + gh[128 + tid])));
            float nval = tanhf(gi[256 + tid] + r * gh[256 + tid]);
            hs[tid] = (1.0f - z) * nval + z * hs[tid];
        }
        __syncthreads();
    }
    if (tid < 128) {
        float a = b_head[tid];
        const float* w = W_head + (size_t)tid * 128;
        float s = 0.f;
        for (int k = 0; k < 128; k += 4) {
            float4 wv = *(const float4*)(w + k);
            s += wv.x * hs[k] + wv.y * hs[k + 1] + wv.z * hs[k + 2] + wv.w * hs[k + 3];
        }
        out[tid] = a + s;
    }
}

// ---------------------------------------------------------------------------

extern "C" void kernel_launch(void* const* d_in, const int* in_sizes, int n_in,
                              void* d_out, int out_size, void* d_ws, size_t ws_size,
                              hipStream_t stream) {
    const float* x_seq  = (const float*)d_in[0];
    const int*   ei_seq = (const int*)d_in[1];
    const float* W1     = (const float*)d_in[2];
    const float* b1     = (const float*)d_in[3];
    const float* W2     = (const float*)d_in[4];
    const float* b2     = (const float*)d_in[5];
    const float* W_ih   = (const float*)d_in[6];
    const float* W_hh   = (const float*)d_in[7];
    const float* b_ih   = (const float*)d_in[8];
    const float* b_hh   = (const float*)d_in[9];
    const float* W_head = (const float*)d_in[10];
    const float* b_head = (const float*)d_in[11];
    float* out = (float*)d_out;

    char* ws = (char*)d_ws;
    size_t off = 0;
    auto alloc = [&](size_t bytes) -> char* {
        char* p = ws + off;
        off += (bytes + 255) & ~(size_t)255;
        return p;
    };
    unsigned* Ys    = (unsigned*)alloc((size_t)NN * 64 * 4);   // bf16 [N][128]
    unsigned* Hbuf  = (unsigned*)alloc((size_t)NN * 64 * 4);   // bf16 [N][128]
    float* dinv     = (float*)alloc((size_t)NN * 4);
    int*   count    = (int*)alloc((size_t)NN * 4);
    int*   row_ptr  = (int*)alloc((size_t)(NN + 1) * 4);
    int*   work     = (int*)alloc((size_t)NN * 4);
    int*   bsum     = (int*)alloc(256 * 4);
    int*   csr_src  = (int*)alloc((size_t)EE * 4);
    float* gseq     = (float*)alloc((size_t)TT * 128 * 4);
    (void)ws_size; (void)n_in; (void)in_sizes; (void)out_size;

    const int gridN  = (NN + 255) / 256;        // 196
    const int gridE  = (EE + 255) / 256;        // 3125
    const int scanB  = (NN + 1023) / 1024;      // 49
    const int gemmB  = (NN + 127) / 128;        // 391
    const int aggB   = (NN + 15) / 16;          // 3125

    for (int t = 0; t < TT; ++t) {
        const int* src = ei_seq + (size_t)t * 2 * EE;
        const int* dst = src + EE;
        const float* Xt = x_seq + (size_t)t * NN * CC;

        zero_counts<<<gridN, 256, 0, stream>>>(count, gseq + t * 128, NN);
        count_edges<<<gridE, 256, 0, stream>>>(dst, count, EE);
        scan1<<<scanB, 256, 0, stream>>>(count, row_ptr, bsum, NN);
        scan2<<<1, 256, 0, stream>>>(bsum, row_ptr, scanB, NN, EE);
        scan3<<<gridN, 256, 0, stream>>>(row_ptr, work, bsum, count, dinv, NN);
        fill_csr<<<gridE, 256, 0, stream>>>(src, dst, work, csr_src, EE);

        gemm_scale_k<false><<<gemmB, 256, 0, stream>>>(Xt, W1, dinv, Ys, NN);
        agg_relu<<<aggB, 256, 0, stream>>>(Ys, csr_src, row_ptr, dinv, b1, Hbuf, NN);
        gemm_scale_k<true><<<gemmB, 256, 0, stream>>>(Hbuf, W2, dinv, Ys, NN);
        agg_relu_pool<<<POOLB, 256, 0, stream>>>(Ys, csr_src, row_ptr, dinv, b2,
                                                 gseq + t * 128, NN);
    }

    gru_head<<<1, 384, 0, stream>>>(gseq, W_ih, W_hh, b_ih, b_hh, W_head, b_head, out);
}

// Round 5
// 3478.365 us; speedup vs baseline: 1.4880x; 1.4880x over previous
//
#include <hip/hip_runtime.h>
#include <hip/hip_bf16.h>
#include <math.h>

#define TT 12
#define NN 50000
#define EE 800000
#define NT (NN * TT)   // 600000 total node-slots
#define ET (EE * TT)   // 9600000 total edges

typedef float f32x4 __attribute__((ext_vector_type(4)));
typedef short bf16x8 __attribute__((ext_vector_type(8)));

__device__ __forceinline__ unsigned short f2bfu(float f) {
    __hip_bfloat16 h = __float2bfloat16(f);   // RNE; compiler fuses pairs to v_cvt_pk_bf16_f32
    return *reinterpret_cast<unsigned short*>(&h);
}
__device__ __forceinline__ float bf_lo(unsigned p) { return __uint_as_float(p << 16); }
__device__ __forceinline__ float bf_hi(unsigned p) { return __uint_as_float(p & 0xFFFF0000u); }

// ---------------------------------------------------------------------------
// Batched CSR build over all 12 graphs (global node ids g = t*NN + n).
// Each graph has exactly EE edges, so a single exclusive scan over the
// concatenated counts yields correct global row_ptr with rp[t*NN] = t*EE.
// ---------------------------------------------------------------------------

__global__ void count_edges_b(const int* __restrict__ ei_seq, int* __restrict__ count) {
    int t = blockIdx.y;
    int e = blockIdx.x * 256 + threadIdx.x;                 // grid.x*256 == EE exactly
    const int* dst = ei_seq + (size_t)t * 2 * EE + EE;
    atomicAdd(&count[t * NN + dst[e]], 1);
}

__global__ __launch_bounds__(256) void scan1(const int* __restrict__ count,
                                             int* __restrict__ rp,
                                             int* __restrict__ bsum) {
    __shared__ int sh[256];
    int tid = threadIdx.x;
    int base = blockIdx.x * 1024 + tid * 4;
    int v0 = (base + 0 < NT) ? count[base + 0] : 0;
    int v1 = (base + 1 < NT) ? count[base + 1] : 0;
    int v2 = (base + 2 < NT) ? count[base + 2] : 0;
    int v3 = (base + 3 < NT) ? count[base + 3] : 0;
    int ts = v0 + v1 + v2 + v3;
    sh[tid] = ts;
    __syncthreads();
    for (int off = 1; off < 256; off <<= 1) {
        int v = (tid >= off) ? sh[tid - off] : 0;
        __syncthreads();
        sh[tid] += v;
        __syncthreads();
    }
    int excl = sh[tid] - ts;
    if (base + 0 < NT) rp[base + 0] = excl;
    if (base + 1 < NT) rp[base + 1] = excl + v0;
    if (base + 2 < NT) rp[base + 2] = excl + v0 + v1;
    if (base + 3 < NT) rp[base + 3] = excl + v0 + v1 + v2;
    if (tid == 255) bsum[blockIdx.x] = sh[255];
}

__global__ __launch_bounds__(1024) void scan2(int* __restrict__ bsum, int* __restrict__ rp, int nb) {
    __shared__ int sh[1024];
    int tid = threadIdx.x;
    int v = (tid < nb) ? bsum[tid] : 0;
    sh[tid] = v;
    __syncthreads();
    for (int off = 1; off < 1024; off <<= 1) {
        int x = (tid >= off) ? sh[tid - off] : 0;
        __syncthreads();
        sh[tid] += x;
        __syncthreads();
    }
    if (tid < nb) bsum[tid] = sh[tid] - v;   // exclusive block offsets
    if (tid == 0) rp[NT] = ET;
}

__global__ void scan3(int* __restrict__ rp, int* __restrict__ work,
                      const int* __restrict__ bsum, const int* __restrict__ count,
                      float* __restrict__ dinv) {
    int i = blockIdx.x * 256 + threadIdx.x;
    if (i < NT) {
        int v = rp[i] + bsum[i >> 10];
        rp[i] = v;
        work[i] = v;
        dinv[i] = rsqrtf(1.0f + (float)count[i]);
    }
}

__global__ void fill_csr_b(const int* __restrict__ ei_seq, int* __restrict__ work,
                           int* __restrict__ csr_src) {
    int t = blockIdx.y;
    int e = blockIdx.x * 256 + threadIdx.x;
    const int* src = ei_seq + (size_t)t * 2 * EE;
    const int* dst = src + EE;
    int g = t * NN + dst[e];
    int pos = atomicAdd(&work[g], 1);
    csr_src[pos] = t * NN + src[e];          // store GLOBAL source row id
}

// ---------------------------------------------------------------------------
// MFMA GEMM: Yb[g][c] = bf16( dinv[g] * sum_k X[g][k] * W[k][c] ), 600000 x 128 @ 128 x 128.
// 256 thr = 4 waves; block covers 320 rows (wave: 5 stripes of 16 rows).
// W staged once per block into LDS in B-fragment order, then held in 128 VGPRs/wave.
// mfma_f32_16x16x32_bf16; A/B k-map: k = ks*32 + (lane>>4)*8 + j (identical for both
// => any consistent k-bijection is correct). C/D: col=lane&15, row=(lane>>4)*4+reg (HW-verified).
// Epilogue transposes through a per-wave LDS tile for coalesced bf16 row stores.
// ---------------------------------------------------------------------------
template<bool XBF16>
__global__ __launch_bounds__(256, 2) void gemm_mfma(const void* __restrict__ Xv,
                                                    const float* __restrict__ W,
                                                    const float* __restrict__ dinv,
                                                    unsigned* __restrict__ Yb) {
    __shared__ unsigned short Wlds[128 * 128];
    __shared__ float tile[4][16 * 132];
    int tid = threadIdx.x;
    // stage W (f32 -> bf16), fragment-ordered: Wlds[((ct*4+ks)*64 + lane)*8 + j]
    //  holds W[k = ks*32 + (lane>>4)*8 + j][c = ct*16 + (lane&15)]
    for (int i = tid * 4; i < 128 * 128; i += 1024) {
        int k = i >> 7;
        float4 w = *(const float4*)&W[i];
        int ks = k >> 5, jg = (k >> 3) & 3, j = k & 7;
#pragma unroll
        for (int q = 0; q < 4; ++q) {
            int c = (i & 127) + q;
            float wv = (q == 0) ? w.x : (q == 1) ? w.y : (q == 2) ? w.z : w.w;
            Wlds[(((c >> 4) * 4 + ks) * 64 + jg * 16 + (c & 15)) * 8 + j] = f2bfu(wv);
        }
    }
    __syncthreads();

    const int wave = tid >> 6, lane = tid & 63;
    const int lg = lane >> 4, lr = lane & 15;

    bf16x8 bfrag[8][4];
#pragma unroll
    for (int ct = 0; ct < 8; ++ct)
#pragma unroll
        for (int ks = 0; ks < 4; ++ks)
            bfrag[ct][ks] = *(const bf16x8*)&Wlds[((ct * 4 + ks) * 64 + lane) * 8];

    const int wbase = blockIdx.x * 320 + wave * 80;
    for (int s = 0; s < 5; ++s) {
        const int rowbase = wbase + s * 16;
        f32x4 acc[8];
#pragma unroll
        for (int ct = 0; ct < 8; ++ct) acc[ct] = (f32x4){0.f, 0.f, 0.f, 0.f};

        if (XBF16) {
            const unsigned short* xr =
                (const unsigned short*)Xv + (size_t)(rowbase + lr) * 128 + lg * 8;
#pragma unroll
            for (int ks = 0; ks < 4; ++ks) {
                bf16x8 af = *(const bf16x8*)(xr + ks * 32);
#pragma unroll
                for (int ct = 0; ct < 8; ++ct)
                    acc[ct] = __builtin_amdgcn_mfma_f32_16x16x32_bf16(af, bfrag[ct][ks], acc[ct], 0, 0, 0);
            }
        } else {
            const float* xr = (const float*)Xv + (size_t)(rowbase + lr) * 128 + lg * 8;
#pragma unroll
            for (int ks = 0; ks < 4; ++ks) {
                float4 a0 = *(const float4*)(xr + ks * 32);
                float4 a1 = *(const float4*)(xr + ks * 32 + 4);
                bf16x8 af;
                af[0] = (short)f2bfu(a0.x); af[1] = (short)f2bfu(a0.y);
                af[2] = (short)f2bfu(a0.z); af[3] = (short)f2bfu(a0.w);
                af[4] = (short)f2bfu(a1.x); af[5] = (short)f2bfu(a1.y);
                af[6] = (short)f2bfu(a1.z); af[7] = (short)f2bfu(a1.w);
#pragma unroll
                for (int ct = 0; ct < 8; ++ct)
                    acc[ct] = __builtin_amdgcn_mfma_f32_16x16x32_bf16(af, bfrag[ct][ks], acc[ct], 0, 0, 0);
            }
        }

        // scale rows by dinv, transpose via per-wave LDS tile (wave-local, no barrier)
        float* tl = tile[wave];
#pragma unroll
        for (int reg = 0; reg < 4; ++reg) {
            float dv = dinv[rowbase + lg * 4 + reg];
#pragma unroll
            for (int ct = 0; ct < 8; ++ct)
                tl[(lg * 4 + reg) * 132 + ct * 16 + lr] = acc[ct][reg] * dv;
        }
#pragma unroll
        for (int p = 0; p < 4; ++p) {
            int flat = p * 512 + lane * 8;
            int row = flat >> 7, col = flat & 127;
            float4 v0 = *(const float4*)&tl[row * 132 + col];
            float4 v1 = *(const float4*)&tl[row * 132 + col + 4];
            uint4 o;
            o.x = f2bfu(v0.x) | ((unsigned)f2bfu(v0.y) << 16);
            o.y = f2bfu(v0.z) | ((unsigned)f2bfu(v0.w) << 16);
            o.z = f2bfu(v1.x) | ((unsigned)f2bfu(v1.y) << 16);
            o.w = f2bfu(v1.z) | ((unsigned)f2bfu(v1.w) << 16);
            *(uint4*)&Yb[(size_t)(rowbase + row) * 64 + (col >> 1)] = o;
        }
    }
}

// ---------------------------------------------------------------------------
// Batched aggregation over bf16 message table (row = 64 u32 = 128 bf16),
// global node ids. out[g] = relu(dinv[g]*(Ys[g] + sum_src Ys[src]) + b).
// ---------------------------------------------------------------------------
__global__ __launch_bounds__(256) void agg_relu_b(const unsigned* __restrict__ Ys,
                                                  const int* __restrict__ csr_src,
                                                  const int* __restrict__ rp,
                                                  const float* __restrict__ dinv,
                                                  const float* __restrict__ bias,
                                                  unsigned* __restrict__ Hout) {
    int wave = threadIdx.x >> 6;
    int lane = threadIdx.x & 63;
    float bx = bias[lane * 2], by = bias[lane * 2 + 1];
    int g0 = blockIdx.x * 16 + wave * 4;
#pragma unroll
    for (int cnt = 0; cnt < 4; ++cnt) {
        int g = g0 + cnt;                    // grid*16 == NT exactly
        unsigned sv = Ys[(size_t)g * 64 + lane];
        float ax = bf_lo(sv), ay = bf_hi(sv);
        float a2x = 0.f, a2y = 0.f;
        int e = rp[g], e1 = rp[g + 1];
        for (; e + 1 < e1; e += 2) {
            unsigned v0 = Ys[(size_t)csr_src[e] * 64 + lane];
            unsigned v1 = Ys[(size_t)csr_src[e + 1] * 64 + lane];
            ax += bf_lo(v0); ay += bf_hi(v0);
            a2x += bf_lo(v1); a2y += bf_hi(v1);
        }
        if (e < e1) {
            unsigned v0 = Ys[(size_t)csr_src[e] * 64 + lane];
            ax += bf_lo(v0); ay += bf_hi(v0);
        }
        float dv = dinv[g];
        float ox = fmaxf((ax + a2x) * dv + bx, 0.f);
        float oy = fmaxf((ay + a2y) * dv + by, 0.f);
        Hout[(size_t)g * 64 + lane] = f2bfu(ox) | ((unsigned)f2bfu(oy) << 16);
    }
}

// Pool variant: grid (64, TT); block strides its graph, one atomicAdd per channel.
__global__ __launch_bounds__(256) void agg_pool_b(const unsigned* __restrict__ Ys,
                                                  const int* __restrict__ csr_src,
                                                  const int* __restrict__ rp,
                                                  const float* __restrict__ dinv,
                                                  const float* __restrict__ bias,
                                                  float* __restrict__ gseq) {
    __shared__ float pool[4][128];
    int t = blockIdx.y;
    int wave = threadIdx.x >> 6;
    int lane = threadIdx.x & 63;
    float bx = bias[lane * 2], by = bias[lane * 2 + 1];
    float px = 0.f, py = 0.f;
    for (int base = blockIdx.x * 16; base < NN; base += 64 * 16) {
        int d0 = base + wave * 4;
#pragma unroll
        for (int cnt = 0; cnt < 4; ++cnt) {
            int g = t * NN + d0 + cnt;       // NN % 16 == 0 -> always in range
            unsigned sv = Ys[(size_t)g * 64 + lane];
            float ax = bf_lo(sv), ay = bf_hi(sv);
            float a2x = 0.f, a2y = 0.f;
            int e = rp[g], e1 = rp[g + 1];
            for (; e + 1 < e1; e += 2) {
                unsigned v0 = Ys[(size_t)csr_src[e] * 64 + lane];
                unsigned v1 = Ys[(size_t)csr_src[e + 1] * 64 + lane];
                ax += bf_lo(v0); ay += bf_hi(v0);
                a2x += bf_lo(v1); a2y += bf_hi(v1);
            }
            if (e < e1) {
                unsigned v0 = Ys[(size_t)csr_src[e] * 64 + lane];
                ax += bf_lo(v0); ay += bf_hi(v0);
            }
            float dv = dinv[g];
            px += fmaxf((ax + a2x) * dv + bx, 0.f);
            py += fmaxf((ay + a2y) * dv + by, 0.f);
        }
    }
    pool[wave][lane * 2] = px;
    pool[wave][lane * 2 + 1] = py;
    __syncthreads();
    int tid = threadIdx.x;
    if (tid < 128) {
        float s = pool[0][tid] + pool[1][tid] + pool[2][tid] + pool[3][tid];
        atomicAdd(&gseq[t * 128 + tid], s);
    }
}

// ---------------------------------------------------------------------------
// GRU over T=12 steps + head. Single block, 384 threads.
// ---------------------------------------------------------------------------
__global__ __launch_bounds__(384) void gru_head(const float* __restrict__ gseq,
                                                const float* __restrict__ W_ih,
                                                const float* __restrict__ W_hh,
                                                const float* __restrict__ b_ih,
                                                const float* __restrict__ b_hh,
                                                const float* __restrict__ W_head,
                                                const float* __restrict__ b_head,
                                                float* __restrict__ out) {
    __shared__ float xs[128], hs[128], gi[384], gh[384];
    int tid = threadIdx.x;
    if (tid < 128) hs[tid] = 0.0f;
    __syncthreads();
    const float inv_n = 1.0f / (float)NN;
    for (int t = 0; t < TT; ++t) {
        if (tid < 128) xs[tid] = gseq[t * 128 + tid] * inv_n;
        __syncthreads();
        float a = b_ih[tid];
        float b = b_hh[tid];
        const float* wi = W_ih + (size_t)tid * 128;
        const float* wh = W_hh + (size_t)tid * 128;
        for (int k = 0; k < 128; k += 4) {
            float4 wiv = *(const float4*)(wi + k);
            float4 whv = *(const float4*)(wh + k);
            float4 xv = *(const float4*)(xs + k);
            float4 hv = *(const float4*)(hs + k);
            a += wiv.x * xv.x + wiv.y * xv.y + wiv.z * xv.z + wiv.w * xv.w;
            b += whv.x * hv.x + whv.y * hv.y + whv.z * hv.z + whv.w * hv.w;
        }
        gi[tid] = a;
        gh[tid] = b;
        __syncthreads();
        if (tid < 128) {
            float r = 1.0f / (1.0f + expf(-(gi[tid] + gh[tid])));
            float z = 1.0f / (1.0f + expf(-(gi[128 + tid] + gh[128 + tid])));
            float nval = tanhf(gi[256 + tid] + r * gh[256 + tid]);
            hs[tid] = (1.0f - z) * nval + z * hs[tid];
        }
        __syncthreads();
    }
    if (tid < 128) {
        float a = b_head[tid];
        const float* w = W_head + (size_t)tid * 128;
        float s = 0.f;
        for (int k = 0; k < 128; k += 4) {
            float4 wv = *(const float4*)(w + k);
            s += wv.x * hs[k] + wv.y * hs[k + 1] + wv.z * hs[k + 2] + wv.w * hs[k + 3];
        }
        out[tid] = a + s;
    }
}

// ---------------------------------------------------------------------------

extern "C" void kernel_launch(void* const* d_in, const int* in_sizes, int n_in,
                              void* d_out, int out_size, void* d_ws, size_t ws_size,
                              hipStream_t stream) {
    const float* x_seq  = (const float*)d_in[0];
    const int*   ei_seq = (const int*)d_in[1];
    const float* W1     = (const float*)d_in[2];
    const float* b1     = (const float*)d_in[3];
    const float* W2     = (const float*)d_in[4];
    const float* b2     = (const float*)d_in[5];
    const float* W_ih   = (const float*)d_in[6];
    const float* W_hh   = (const float*)d_in[7];
    const float* b_ih   = (const float*)d_in[8];
    const float* b_hh   = (const float*)d_in[9];
    const float* W_head = (const float*)d_in[10];
    const float* b_head = (const float*)d_in[11];
    float* out = (float*)d_out;

    char* ws = (char*)d_ws;
    size_t off = 0;
    auto alloc = [&](size_t bytes) -> char* {
        char* p = ws + off;
        off += (bytes + 255) & ~(size_t)255;
        return p;
    };
    unsigned* Ys    = (unsigned*)alloc((size_t)NT * 64 * 4);   // bf16 [NT][128]  153.6MB
    unsigned* Hbuf  = (unsigned*)alloc((size_t)NT * 64 * 4);   // bf16 [NT][128]  153.6MB
    float* dinv     = (float*)alloc((size_t)NT * 4);
    int*   count    = (int*)alloc((size_t)NT * 4);
    int*   row_ptr  = (int*)alloc((size_t)(NT + 1) * 4);
    int*   work     = (int*)alloc((size_t)NT * 4);
    int*   bsum     = (int*)alloc(1024 * 4);
    int*   csr_src  = (int*)alloc((size_t)ET * 4);             // 38.4MB
    float* gseq     = (float*)alloc((size_t)TT * 128 * 4);
    (void)ws_size; (void)n_in; (void)in_sizes; (void)out_size;

    const int scanB = (NT + 1023) / 1024;   // 586

    hipMemsetAsync(count, 0, (size_t)NT * 4, stream);
    hipMemsetAsync(gseq, 0, (size_t)TT * 128 * 4, stream);

    count_edges_b<<<dim3(EE / 256, TT), 256, 0, stream>>>(ei_seq, count);
    scan1<<<scanB, 256, 0, stream>>>(count, row_ptr, bsum);
    scan2<<<1, 1024, 0, stream>>>(bsum, row_ptr, scanB);
    scan3<<<(NT + 255) / 256, 256, 0, stream>>>(row_ptr, work, bsum, count, dinv);
    fill_csr_b<<<dim3(EE / 256, TT), 256, 0, stream>>>(ei_seq, work, csr_src);

    gemm_mfma<false><<<NT / 320, 256, 0, stream>>>(x_seq, W1, dinv, Ys);
    agg_relu_b<<<NT / 16, 256, 0, stream>>>(Ys, csr_src, row_ptr, dinv, b1, Hbuf);
    gemm_mfma<true><<<NT / 320, 256, 0, stream>>>(Hbuf, W2, dinv, Ys);
    agg_pool_b<<<dim3(64, TT), 256, 0, stream>>>(Ys, csr_src, row_ptr, dinv, b2, gseq);

    gru_head<<<1, 384, 0, stream>>>(gseq, W_ih, W_hh, b_ih, b_hh, W_head, b_head, out);
}